// Round 1
// baseline (289.607 us; speedup 1.0000x reference)
//
#include <hip/hip_runtime.h>

typedef unsigned short ushort_t;
typedef __attribute__((ext_vector_type(8))) short short8;
typedef __attribute__((ext_vector_type(4))) float floatx4;

__device__ __forceinline__ unsigned short f2bf(float f) {
  unsigned int u = __float_as_uint(f);
  u += 0x7fffu + ((u >> 16) & 1u);
  return (unsigned short)(u >> 16);
}

__device__ __forceinline__ void gl_lds16(const void* g, void* l) {
  __builtin_amdgcn_global_load_lds((const __attribute__((address_space(1))) void*)g,
                                   (__attribute__((address_space(3))) void*)l,
                                   16, 0, 0);
}

// ---------------- prep kernels ----------------

__global__ void conv_x_kernel(const float* __restrict__ src, ushort_t* __restrict__ dst, int n4) {
  int i = blockIdx.x * blockDim.x + threadIdx.x;
  if (i >= n4) return;
  float4 v = ((const float4*)src)[i];
  union { ushort_t u[4]; unsigned long long ll; } o;
  o.u[0] = f2bf(v.x); o.u[1] = f2bf(v.y); o.u[2] = f2bf(v.z); o.u[3] = f2bf(v.w);
  ((unsigned long long*)dst)[i] = o.ll;
}

// src fp32 [R][C] row-major  ->  dst bf16 [C][R] row-major (row stride R)
__global__ void transpose_conv(const float* __restrict__ src, ushort_t* __restrict__ dst,
                               int R, int C) {
  __shared__ float tile[32][33];
  int c0 = blockIdx.x * 32, r0 = blockIdx.y * 32;
  int tx = threadIdx.x, ty = threadIdx.y;
#pragma unroll
  for (int i = ty; i < 32; i += 8)
    tile[i][tx] = src[(long)(r0 + i) * C + c0 + tx];
  __syncthreads();
#pragma unroll
  for (int i = ty; i < 32; i += 8)
    dst[(long)(c0 + i) * R + r0 + tx] = f2bf(tile[tx][i]);
}

// ---------------- GEMM: C[M,N] = A[M,K] * B^T (B stored [N][K]), bf16 in, fp32 acc ----------------
// EPI=0: QKV epilogue (N=3072): n<2048 -> q_buf [32][2048][64] (scaled 0.125),
//        n<2560 -> k_buf [8][2048][64], else v^T buf [8][64][2048]
// EPI=1: fp32 C output
template <int EPI>
__global__ __launch_bounds__(256, 2) void gemm_bt(
    const ushort_t* __restrict__ A, const ushort_t* __restrict__ B,
    float* __restrict__ C,
    ushort_t* __restrict__ qb, ushort_t* __restrict__ kb, ushort_t* __restrict__ vb,
    int M, int N, int K) {
  __shared__ ushort_t As[128 * 32];
  __shared__ ushort_t Bs[128 * 32];
  const int t = threadIdx.x;
  const int w = t >> 6, lane = t & 63;
  const int m = lane & 15, quad = lane >> 4;
  const int m0 = blockIdx.y * 128, n0 = blockIdx.x * 128;
  const int wr = w >> 1, wc = w & 1;

  floatx4 acc[4][4] = {};

  for (int kk = 0; kk < K; kk += 32) {
    __syncthreads();
#pragma unroll
    for (int i = 0; i < 2; ++i) {
      int c = i * 256 + t;
      int c0 = i * 256 + w * 64;
      gl_lds16(A + (long)(m0 + (c >> 2)) * K + kk + (c & 3) * 8, As + c0 * 8);
      gl_lds16(B + (long)(n0 + (c >> 2)) * K + kk + (c & 3) * 8, Bs + c0 * 8);
    }
    __syncthreads();
    short8 af[4], bf[4];
#pragma unroll
    for (int i = 0; i < 4; ++i)
      af[i] = *(const short8*)(As + (wr * 64 + i * 16 + m) * 32 + quad * 8);
#pragma unroll
    for (int j = 0; j < 4; ++j)
      bf[j] = *(const short8*)(Bs + (wc * 64 + j * 16 + m) * 32 + quad * 8);
#pragma unroll
    for (int i = 0; i < 4; ++i)
#pragma unroll
      for (int j = 0; j < 4; ++j)
        acc[i][j] = __builtin_amdgcn_mfma_f32_16x16x32_bf16(af[i], bf[j], acc[i][j], 0, 0, 0);
  }

#pragma unroll
  for (int i = 0; i < 4; ++i)
#pragma unroll
    for (int j = 0; j < 4; ++j)
#pragma unroll
      for (int r = 0; r < 4; ++r) {
        float v = acc[i][j][r];
        int row = m0 + wr * 64 + i * 16 + quad * 4 + r;
        int col = n0 + wc * 64 + j * 16 + m;
        if (EPI == 1) {
          C[(long)row * N + col] = v;
        } else {
          if (col < 2048) {
            qb[((((col >> 6) * 2048) + row) << 6) | (col & 63)] = f2bf(v * 0.125f);
          } else if (col < 2560) {
            int g = (col - 2048) >> 6;
            kb[(((g * 2048) + row) << 6) | (col & 63)] = f2bf(v);
          } else {
            int g = (col - 2560) >> 6;
            vb[(long)((g << 6) | (col & 63)) * 2048 + row] = f2bf(v);
          }
        }
      }
}

// ---------------- flash attention ----------------
// Q [32][S][64] bf16 (pre-scaled), K [8][S][64] bf16, V^T [8][64][S] bf16 -> O [S][2048] bf16
__global__ __launch_bounds__(256, 2) void flash_kernel(
    const ushort_t* __restrict__ Q, const ushort_t* __restrict__ Kb,
    const ushort_t* __restrict__ Vb, ushort_t* __restrict__ O, int S) {
  __shared__ ushort_t Ks[2 * 128 * 32];     // [kq][krow][32]
  __shared__ ushort_t Vs[4 * 64 * 32];      // [kt][c][32]
  __shared__ ushort_t Ps[4 * 4 * 32 * 32];  // per-wave [kt][row][32]
  const int t = threadIdx.x;
  const int w = t >> 6, lane = t & 63;
  const int m = lane & 15, quad = lane >> 4;
  const int h = blockIdx.y, g = h >> 2;
  const int q0 = blockIdx.x * 128;
  const ushort_t* qp = Q + (long)h * S * 64;
  const ushort_t* kp = Kb + (long)g * S * 64;
  const ushort_t* vp = Vb + (long)g * 64 * S;

  short8 qf[2][2];
#pragma unroll
  for (int rt = 0; rt < 2; ++rt)
#pragma unroll
    for (int kq = 0; kq < 2; ++kq)
      qf[rt][kq] = *(const short8*)(qp + (long)(q0 + w * 32 + rt * 16 + m) * 64 + kq * 32 + quad * 8);

  float mrow[2][4], lrow[2][4];
  floatx4 oacc[2][4] = {};
#pragma unroll
  for (int rt = 0; rt < 2; ++rt)
#pragma unroll
    for (int r = 0; r < 4; ++r) { mrow[rt][r] = -1e30f; lrow[rt][r] = 0.f; }

  ushort_t* Pw = Ps + w * 4096;

  for (int t0 = 0; t0 < S; t0 += 128) {
    __syncthreads();
#pragma unroll
    for (int i = 0; i < 4; ++i) {
      int c = i * 256 + t;
      int c0 = i * 256 + w * 64;
      gl_lds16(kp + (long)(t0 + ((c >> 2) & 127)) * 64 + (c >> 9) * 32 + (c & 3) * 8, Ks + c0 * 8);
      gl_lds16(vp + (long)((c >> 2) & 63) * S + t0 + (c >> 8) * 32 + (c & 3) * 8, Vs + c0 * 8);
    }
    __syncthreads();

    floatx4 sacc[2][8] = {};
#pragma unroll
    for (int ct = 0; ct < 8; ++ct) {
      short8 kf0 = *(const short8*)(Ks + (ct * 16 + m) * 32 + quad * 8);
      short8 kf1 = *(const short8*)(Ks + 4096 + (ct * 16 + m) * 32 + quad * 8);
#pragma unroll
      for (int rt = 0; rt < 2; ++rt) {
        sacc[rt][ct] = __builtin_amdgcn_mfma_f32_16x16x32_bf16(qf[rt][0], kf0, sacc[rt][ct], 0, 0, 0);
        sacc[rt][ct] = __builtin_amdgcn_mfma_f32_16x16x32_bf16(qf[rt][1], kf1, sacc[rt][ct], 0, 0, 0);
      }
    }

    float mnew[2][4], al[2][4], ls[2][4];
#pragma unroll
    for (int rt = 0; rt < 2; ++rt)
#pragma unroll
      for (int r = 0; r < 4; ++r) {
        float mx = sacc[rt][0][r];
#pragma unroll
        for (int ct = 1; ct < 8; ++ct) mx = fmaxf(mx, sacc[rt][ct][r]);
#pragma unroll
        for (int s = 1; s < 16; s <<= 1) mx = fmaxf(mx, __shfl_xor(mx, s));
        mnew[rt][r] = fmaxf(mrow[rt][r], mx);
        al[rt][r] = __expf(mrow[rt][r] - mnew[rt][r]);
        ls[rt][r] = 0.f;
      }

#pragma unroll
    for (int rt = 0; rt < 2; ++rt)
#pragma unroll
      for (int ct = 0; ct < 8; ++ct) {
        int kt = ct >> 1;
        int colbase = (ct & 1) * 16 + m;
#pragma unroll
        for (int r = 0; r < 4; ++r) {
          float p = __expf(sacc[rt][ct][r] - mnew[rt][r]);
          ls[rt][r] += p;
          int row = rt * 16 + quad * 4 + r;
          Pw[kt * 1024 + row * 32 + colbase] = f2bf(p);
        }
      }

#pragma unroll
    for (int rt = 0; rt < 2; ++rt)
#pragma unroll
      for (int r = 0; r < 4; ++r) {
        float s_ = ls[rt][r];
#pragma unroll
        for (int s = 1; s < 16; s <<= 1) s_ += __shfl_xor(s_, s);
        lrow[rt][r] = lrow[rt][r] * al[rt][r] + s_;
        mrow[rt][r] = mnew[rt][r];
      }

#pragma unroll
    for (int rt = 0; rt < 2; ++rt)
#pragma unroll
      for (int ct = 0; ct < 4; ++ct)
#pragma unroll
        for (int r = 0; r < 4; ++r)
          oacc[rt][ct][r] *= al[rt][r];

#pragma unroll
    for (int kt = 0; kt < 4; ++kt) {
      short8 pf[2];
#pragma unroll
      for (int rt = 0; rt < 2; ++rt)
        pf[rt] = *(const short8*)(Pw + kt * 1024 + (rt * 16 + m) * 32 + quad * 8);
#pragma unroll
      for (int ct = 0; ct < 4; ++ct) {
        short8 vf = *(const short8*)(Vs + kt * 2048 + (ct * 16 + m) * 32 + quad * 8);
#pragma unroll
        for (int rt = 0; rt < 2; ++rt)
          oacc[rt][ct] = __builtin_amdgcn_mfma_f32_16x16x32_bf16(pf[rt], vf, oacc[rt][ct], 0, 0, 0);
      }
    }
  }

#pragma unroll
  for (int rt = 0; rt < 2; ++rt)
#pragma unroll
    for (int r = 0; r < 4; ++r) {
      float inv = 1.f / lrow[rt][r];
      int srow = q0 + w * 32 + rt * 16 + quad * 4 + r;
#pragma unroll
      for (int ct = 0; ct < 4; ++ct)
        O[(long)srow * 2048 + h * 64 + ct * 16 + m] = f2bf(oacc[rt][ct][r] * inv);
    }
}

// ---------------- launch ----------------

extern "C" void kernel_launch(void* const* d_in, const int* in_sizes, int n_in,
                              void* d_out, int out_size, void* d_ws, size_t ws_size,
                              hipStream_t stream) {
  (void)in_sizes; (void)n_in; (void)out_size; (void)ws_size;
  const float* x  = (const float*)d_in[0];
  const float* wq = (const float*)d_in[1];
  const float* wk = (const float*)d_in[2];
  const float* wv = (const float*)d_in[3];
  const float* wo = (const float*)d_in[4];
  float* out = (float*)d_out;
  char* ws = (char*)d_ws;
  const size_t MB = 1u << 20;

  ushort_t* xb    = (ushort_t*)(ws);            // 8 MB  x bf16 [2048][2048]
  ushort_t* wqkvT = (ushort_t*)(ws + 8 * MB);   // 12 MB [3072][2048]
  ushort_t* woT   = (ushort_t*)(ws + 20 * MB);  // 8 MB  [2048][2048]
  ushort_t* qbuf  = (ushort_t*)(ws + 28 * MB);  // 8 MB  [32][2048][64]
  ushort_t* kbuf  = (ushort_t*)(ws + 36 * MB);  // 2 MB  [8][2048][64]
  ushort_t* vbuf  = (ushort_t*)(ws + 38 * MB);  // 2 MB  [8][64][2048]
  ushort_t* attn  = xb;                         // alias: xb dead after gemm<0>

  conv_x_kernel<<<4096, 256, 0, stream>>>(x, xb, 2048 * 2048 / 4);
  dim3 tb(32, 8);
  transpose_conv<<<dim3(64, 64), tb, 0, stream>>>(wq, wqkvT, 2048, 2048);
  transpose_conv<<<dim3(16, 64), tb, 0, stream>>>(wk, wqkvT + 2048 * 2048, 2048, 512);
  transpose_conv<<<dim3(16, 64), tb, 0, stream>>>(wv, wqkvT + 2560 * 2048, 2048, 512);
  transpose_conv<<<dim3(64, 64), tb, 0, stream>>>(wo, woT, 2048, 2048);

  gemm_bt<0><<<dim3(24, 16), 256, 0, stream>>>(xb, wqkvT, nullptr, qbuf, kbuf, vbuf,
                                               2048, 3072, 2048);
  flash_kernel<<<dim3(16, 32), 256, 0, stream>>>(qbuf, kbuf, vbuf, attn, 2048);
  gemm_bt<1><<<dim3(16, 16), 256, 0, stream>>>(attn, woT, out, nullptr, nullptr, nullptr,
                                               2048, 2048, 2048);
}